// Round 1
// 705.363 us; speedup vs baseline: 1.0187x; 1.0187x over previous
//
#include <hip/hip_runtime.h>

#define H 192
#define W 192
#define HW (H*W)
#define G 32          // feature/ctx channels
#define C 64          // x channels
#define C2 128        // mean+var channels
#define C1 68         // conv1 out channels
#define B 6           // output batches
#define NB 2          // distinct ctx batches
#define OUTC 260      // 68 + 3*64
#define STRIP 48      // rows per mv block (old path)
#define STRIP_R 48    // rows per mv_all block (new path)

// ---------------- shared front kernels ----------------

// K1: img_ctx[b][o][p] = b_ctx[o] + sum_k w_ctx[o][k] * feature[b][k][p], b in 0..1
__global__ __launch_bounds__(256) void ctx_kernel(
    const float* __restrict__ feature, const float* __restrict__ w_ctx,
    const float* __restrict__ b_ctx, float* __restrict__ ctx)
{
    int p = blockIdx.x * 256 + threadIdx.x;
    int b = blockIdx.y;
    float f[G];
    const float* fp = feature + (size_t)b * G * HW + p;
#pragma unroll
    for (int k = 0; k < G; k++) f[k] = fp[k * HW];
    float* op = ctx + (size_t)b * G * HW + p;
    for (int o = 0; o < G; o++) {
        float acc = b_ctx[o];
#pragma unroll
        for (int k = 0; k < G; k++) acc += w_ctx[o * G + k] * f[k];
        op[o * HW] = acc;
    }
}

// K2: out[b][o][p] = b1[o] + sum_c w1[o][c] * x[b][c][p], o in 0..67
__global__ __launch_bounds__(256) void conv1_kernel(
    const float* __restrict__ ctx, const float* __restrict__ extra,
    const float* __restrict__ w1, const float* __restrict__ b1,
    float* __restrict__ out)
{
    int p = blockIdx.x * 256 + threadIdx.x;
    int b = blockIdx.y;
    float xv[C];
    const float* cp = ctx + (size_t)(b / 3) * G * HW + p;
#pragma unroll
    for (int k = 0; k < G; k++) xv[k] = cp[k * HW];
    const float* ep = extra + (size_t)b * G * HW + p;
#pragma unroll
    for (int k = 0; k < G; k++) xv[G + k] = ep[k * HW];
    float* op = out + (size_t)b * OUTC * HW + p;
    for (int o = 0; o < C1; o++) {
        float acc = b1[o];
#pragma unroll
        for (int k = 0; k < C; k++) acc += w1[o * C + k] * xv[k];
        op[o * HW] = acc;
    }
}

// ---------------- NEW path: scan-based fused mv + fused sconv ----------------

// DPP wave64 inclusive scan (LLVM AtomicOptimizer pattern):
// shr1, shr2, shr4, shr8, bcast15(rows 1,3), bcast31(rows 2,3); old=0 identity.
template<int CTRL, int RM>
__device__ __forceinline__ float dpp_mov0(float x) {
    return __int_as_float(__builtin_amdgcn_update_dpp(
        0, __float_as_int(x), CTRL, RM, 0xf, false));
}
__device__ __forceinline__ float wave_iscan(float x) {
    x += dpp_mov0<0x111, 0xf>(x);   // row_shr:1
    x += dpp_mov0<0x112, 0xf>(x);   // row_shr:2
    x += dpp_mov0<0x114, 0xf>(x);   // row_shr:4
    x += dpp_mov0<0x118, 0xf>(x);   // row_shr:8
    x += dpp_mov0<0x142, 0xa>(x);   // row_bcast:15 -> rows 1,3
    x += dpp_mov0<0x143, 0xc>(x);   // row_bcast:31 -> rows 2,3
    return x;
}

// weights for sconv, interleaved: wTi[si][c][0..63]=mean w, wTi[si][c][64..127]=var w
__global__ __launch_bounds__(256) void transpose_wi_kernel(
    const float* __restrict__ w0, const float* __restrict__ w1,
    const float* __restrict__ w2, float* __restrict__ wTi)
{
    int i = blockIdx.x * 256 + threadIdx.x;
    if (i >= 3 * C * C2) return;
    int si = i / (C * C2);
    int r = i % (C * C2);
    const float* ws = (si == 0) ? w0 : (si == 1) ? w1 : w2;
    int o = r / C2, ci = r % C2;
    int dst = (ci < C) ? (ci * (2 * C) + o) : ((ci - C) * (2 * C) + C + o);
    wTi[si * (C2 * C) + dst] = ws[r];
}

// K3': all 3 scales in one pass. One block = (channel c, row-strip, batch).
// Vertical running sums in regs; horizontal box via DPP prefix scan + 2 LDS
// reads per scale. Output mv[si][bz][c][p] as float2 {mean, var}.
__global__ __launch_bounds__(192) void mv_all_kernel(
    const float* __restrict__ ctx, const float* __restrict__ extra,
    int bbase, int nbs, float* __restrict__ mv)
{
    __shared__ float2 pls[2][3][W];    // [buf][scale][col] full prefix (s1,s2)
    __shared__ float2 wsum[2][3][3];   // [buf][scale][wave] wave totals
    const int hk0 = 2, hk1 = 4, hk2 = 8;
    const int hks[3] = {hk0, hk1, hk2};

    int w = threadIdx.x;
    int lane = w & 63;
    int wv = w >> 6;
    int c = blockIdx.x;
    int bz = blockIdx.z;
    int b = bbase + bz;
    const float* src = (c < G) ? (ctx + ((size_t)(b / 3) * G + c) * HW)
                               : (extra + ((size_t)b * G + (c - G)) * HW);
    int h0 = blockIdx.y * STRIP_R;

    // init vertical running windows at h0 (out-of-range rows contribute 0;
    // area correction handled via nrows)
    float s1[3] = {0.f, 0.f, 0.f}, s2[3] = {0.f, 0.f, 0.f};
#pragma unroll
    for (int dy = -hk2; dy <= hk2; ++dy) {
        int y = h0 + dy;
        float v = (y >= 0 && y < H) ? src[y * W + w] : 0.f;
        float vv = v * v;
        if (dy >= -hk0 && dy <= hk0) { s1[0] += v; s2[0] += vv; }
        if (dy >= -hk1 && dy <= hk1) { s1[1] += v; s2[1] += vv; }
        s1[2] += v; s2[2] += vv;
    }

    // per-thread horizontal window constants
    float inv_nc[3];
    int x1i[3], x0m[3];
#pragma unroll
    for (int k = 0; k < 3; ++k) {
        int x0 = max(w - hks[k], 0), x1 = min(w + hks[k], W - 1);
        x1i[k] = x1;
        x0m[k] = w - hks[k] - 1;
        inv_nc[k] = 1.0f / (float)(x1 - x0 + 1);
    }
    size_t sstride = (size_t)nbs * C * HW;          // float2 elems per scale
    float2* mvp = (float2*)mv + ((size_t)bz * C + c) * HW;

    for (int h = h0; h < h0 + STRIP_R; ++h) {
        if (h > h0) {
#pragma unroll
            for (int k = 0; k < 3; ++k) {
                int ya = h + hks[k], ys = h - hks[k] - 1;
                if (ya < H)  { float v = src[ya * W + w]; s1[k] += v; s2[k] = fmaf(v, v, s2[k]); }
                if (ys >= 0) { float v = src[ys * W + w]; s1[k] -= v; s2[k] = fmaf(-v, v, s2[k]); }
            }
        }
        int buf = h & 1;
        float p1[3], p2[3];
#pragma unroll
        for (int k = 0; k < 3; ++k) { p1[k] = wave_iscan(s1[k]); p2[k] = wave_iscan(s2[k]); }
        if (lane == 63) {
#pragma unroll
            for (int k = 0; k < 3; ++k) wsum[buf][k][wv] = make_float2(p1[k], p2[k]);
        }
        __syncthreads();
#pragma unroll
        for (int k = 0; k < 3; ++k) {
            float2 w0v = wsum[buf][k][0];
            float2 w1v = wsum[buf][k][1];
            float o1 = 0.f, o2 = 0.f;
            if (wv >= 1) { o1 += w0v.x; o2 += w0v.y; }
            if (wv >= 2) { o1 += w1v.x; o2 += w1v.y; }
            pls[buf][k][w] = make_float2(p1[k] + o1, p2[k] + o2);
        }
        __syncthreads();
#pragma unroll
        for (int k = 0; k < 3; ++k) {
            float2 hi = pls[buf][k][x1i[k]];
            int xm = x0m[k];
            float2 lo = pls[buf][k][xm < 0 ? 0 : xm];
            if (xm < 0) { lo.x = 0.f; lo.y = 0.f; }
            float t1 = hi.x - lo.x;
            float t2 = hi.y - lo.y;
            float inv_nr;
            if (h >= hks[k] && h + hks[k] < H) inv_nr = 1.0f / (float)(2 * hks[k] + 1);
            else inv_nr = 1.0f / (float)(min(h + hks[k], H - 1) - max(h - hks[k], 0) + 1);
            float ia = inv_nr * inv_nc[k];
            float mean = t1 * ia;
            float var = fmaf(t2, ia, -(mean * mean));
            mvp[(size_t)k * sstride + h * W + w] = make_float2(mean, var);
        }
    }
}

// K4': fused 1x1 conv 128->64 for all 3 scales (z = scale), float2 mv reads.
__global__ __launch_bounds__(256) void sconv_all_kernel(
    const float* __restrict__ mv, const float* __restrict__ wTi,
    const float* __restrict__ bs0, const float* __restrict__ bs1,
    const float* __restrict__ bs2,
    int bbase, int nbs, float* __restrict__ out)
{
    int p = blockIdx.x * 256 + threadIdx.x;
    int bz = blockIdx.y;
    int si = blockIdx.z;
    size_t sstride = (size_t)nbs * C * HW;
    const float2* xp = (const float2*)mv + (size_t)si * sstride + (size_t)bz * C * HW + p;
    const float* wp = wTi + si * (C2 * C);
    float acc[C];
#pragma unroll
    for (int o = 0; o < C; ++o) acc[o] = 0.f;
#pragma unroll 2
    for (int c = 0; c < C; ++c) {
        float2 v = xp[(size_t)c * HW];
        const float* wrow = wp + c * (2 * C);
#pragma unroll
        for (int o = 0; o < C; ++o)
            acc[o] = fmaf(wrow[o], v.x, fmaf(wrow[C + o], v.y, acc[o]));
    }
    const float* bs = (si == 0) ? bs0 : (si == 1) ? bs1 : bs2;
    float* op = out + ((size_t)(bbase + bz) * OUTC + C1 + si * C) * HW + p;
#pragma unroll
    for (int o = 0; o < C; ++o) op[o * HW] = acc[o] + bs[o];
}

// ---------------- OLD path kernels (fallback, verified) ----------------

__global__ __launch_bounds__(256) void transpose_w_kernel(
    const float* __restrict__ wsrc, float* __restrict__ wT, int oc, int ic)
{
    int i = blockIdx.x * 256 + threadIdx.x;
    if (i >= oc * ic) return;
    int o = i / ic, c = i % ic;
    wT[c * oc + o] = wsrc[i];
}

__global__ __launch_bounds__(192) void mv_kernel(
    const float* __restrict__ ctx, const float* __restrict__ extra,
    int half, int bbase, float* __restrict__ mv)
{
    __shared__ float ls1[2][W];
    __shared__ float ls2[2][W];
    int w = threadIdx.x;
    int c = blockIdx.x;
    int s = blockIdx.y;
    int bz = blockIdx.z;
    int b = bbase + bz;
    const float* src = (c < G)
        ? (ctx + ((size_t)(b / 3) * G + c) * HW)
        : (extra + ((size_t)b * G + (c - G)) * HW);

    int h0 = s * STRIP;
    int ya = max(h0 - half, 0);
    int yb = min(h0 + half, H - 1);
    float s1 = 0.f, s2 = 0.f;
    for (int y = ya; y <= yb; y++) { float v = src[y * W + w]; s1 += v; s2 += v * v; }

    int x0 = max(w - half, 0);
    int x1 = min(w + half, W - 1);
    float ncols = (float)(x1 - x0 + 1);

    size_t obase = ((size_t)bz * C2 + c) * HW;

    for (int h = h0; h < h0 + STRIP; h++) {
        if (h > h0) {
            int yadd = h + half;
            int ysub = h - half - 1;
            if (yadd <= H - 1) { float v = src[yadd * W + w]; s1 += v; s2 += v * v; }
            if (ysub >= 0)     { float v = src[ysub * W + w]; s1 -= v; s2 -= v * v; }
        }
        int buf = h & 1;
        ls1[buf][w] = s1;
        ls2[buf][w] = s2;
        __syncthreads();
        float t1 = 0.f, t2 = 0.f;
        for (int x = x0; x <= x1; x++) { t1 += ls1[buf][x]; t2 += ls2[buf][x]; }
        int nrows = min(h + half, H - 1) - max(h - half, 0) + 1;
        float inv_area = 1.0f / ((float)nrows * ncols);
        float mean = t1 * inv_area;
        float var  = t2 * inv_area - mean * mean;
        mv[obase + h * W + w] = mean;
        mv[obase + (size_t)C * HW + h * W + w] = var;
    }
}

__global__ __launch_bounds__(256) void sconv_kernel(
    const float* __restrict__ mv, const float* __restrict__ wT,
    const float* __restrict__ bsc, int bbase, int co, float* __restrict__ out)
{
    int p = blockIdx.x * 256 + threadIdx.x;
    int bz = blockIdx.y;
    int b = bbase + bz;
    const float* xp = mv + (size_t)bz * C2 * HW + p;
    float acc[C];
#pragma unroll
    for (int o = 0; o < C; o++) acc[o] = 0.f;
#pragma unroll 2
    for (int c = 0; c < C2; c++) {
        float v = xp[(size_t)c * HW];
        const float* wrow = wT + c * C;
#pragma unroll
        for (int o = 0; o < C; o++) acc[o] += wrow[o] * v;
    }
    float* op = out + ((size_t)b * OUTC + co) * HW + p;
#pragma unroll
    for (int o = 0; o < C; o++) op[o * HW] = acc[o] + bsc[o];
}

// ---------------- launch ----------------

extern "C" void kernel_launch(void* const* d_in, const int* in_sizes, int n_in,
                              void* d_out, int out_size, void* d_ws, size_t ws_size,
                              hipStream_t stream) {
    const float* feature = (const float*)d_in[0];
    const float* extra   = (const float*)d_in[1];
    const float* w_ctx   = (const float*)d_in[2];
    const float* b_ctx   = (const float*)d_in[3];
    const float* w1      = (const float*)d_in[4];
    const float* b1      = (const float*)d_in[5];
    const float* w_s[3]  = {(const float*)d_in[6], (const float*)d_in[8], (const float*)d_in[10]};
    const float* b_s[3]  = {(const float*)d_in[7], (const float*)d_in[9], (const float*)d_in[11]};
    float* out = (float*)d_out;

    // ws layout (floats)
    float* ctx = (float*)d_ws;                       // NB*G*HW
    float* wT  = ctx + (size_t)NB * G * HW;          // 3 * C2*C (planar or interleaved)
    float* mv  = wT + 3 * C2 * C;                    // new: B*3*C*HW*2 ; old: nb*C2*HW

    size_t base_bytes = ((size_t)NB * G * HW + 3 * C2 * C) * 4;
    size_t mv_new = (size_t)B * 3 * C * HW * 2 * 4;  // 6 slots x 3 scales, float2
    size_t mv_full = (size_t)B * C2 * HW * 4;        // old batched
    bool newpath = ws_size >= base_bytes + mv_new;

    ctx_kernel<<<dim3(HW / 256, NB), 256, 0, stream>>>(feature, w_ctx, b_ctx, ctx);
    conv1_kernel<<<dim3(HW / 256, B), 256, 0, stream>>>(ctx, extra, w1, b1, out);

    if (newpath) {
        transpose_wi_kernel<<<dim3((3 * C * C2 + 255) / 256), 256, 0, stream>>>(
            w_s[0], w_s[1], w_s[2], wT);
        mv_all_kernel<<<dim3(C, H / STRIP_R, B), W, 0, stream>>>(ctx, extra, 0, B, mv);
        sconv_all_kernel<<<dim3(HW / 256, B, 3), 256, 0, stream>>>(
            mv, wT, b_s[0], b_s[1], b_s[2], 0, B, out);
    } else {
        for (int si = 0; si < 3; si++) {
            transpose_w_kernel<<<dim3((C2 * C + 255) / 256), 256, 0, stream>>>(
                w_s[si], wT + si * C2 * C, C, C2);
        }
        const int halves[3] = {2, 4, 8};
        bool batched = ws_size >= base_bytes + mv_full;
        if (batched) {
            for (int si = 0; si < 3; si++) {
                mv_kernel<<<dim3(C, H / STRIP, B), W, 0, stream>>>(ctx, extra, halves[si], 0, mv);
                sconv_kernel<<<dim3(HW / 256, B), 256, 0, stream>>>(
                    mv, wT + si * C2 * C, b_s[si], 0, C1 + si * C, out);
            }
        } else {
            for (int si = 0; si < 3; si++) {
                for (int b = 0; b < B; b++) {
                    mv_kernel<<<dim3(C, H / STRIP, 1), W, 0, stream>>>(ctx, extra, halves[si], b, mv);
                    sconv_kernel<<<dim3(HW / 256, 1), 256, 0, stream>>>(
                        mv, wT + si * C2 * C, b_s[si], b, C1 + si * C, out);
                }
            }
        }
    }
}